// Round 2
// baseline (408.295 us; speedup 1.0000x reference)
//
#include <hip/hip_runtime.h>

// ---------------------------------------------------------------------------
// LRU single step, fused — v3 (swapped-operand MFMA: h/o on the reg axis).
//   state = Lambda * x0 + Bn @ u              (complex; stored PLANAR re|im)
//   y     = s_re @ C_re^T - s_im @ C_im^T + u @ D^T
// Weights:
//   W1 [1024][256] bf16 chunked-planar: rows s*256+[0,128) = Bn_re[h=s*128+j],
//                                       rows s*256+[128,256) = Bn_im[same h]
//   Wy [256][1280] bf16 chunked:  cols s*256+[0,128)  = C_re[o][s*128+j],
//                                 cols s*256+[128,256) = -C_im[o][s*128+j],
//                                 cols [1024,1280)     = D
// MFMA convention: A-operand = weights (M = h-plane / o), B-operand =
// activations (N = n). D fragment: row (quad*4+reg) = M, col (l16) = N.
// => each lane owns 4 CONSECUTIVE h (or o) for a fixed n: state math and all
// global stores/loads are per-lane f32x4 with full 64B-segment coverage
// (quads 0..3 of an l16 group cover 64 contiguous bytes). No f32 LDS
// transpose buffers, no Bu round-trip. LDS = Xu + Sc = 34 KB -> 3 blocks/CU.
// ---------------------------------------------------------------------------

typedef __attribute__((ext_vector_type(8))) short bf16x8;
typedef __attribute__((ext_vector_type(4))) float f32x4;
typedef unsigned short u16;

#define N_ROWS 32768
#define IN_DIM 256
#define SD 512
#define OUT_DIM 256
#define ROWS 32          // rows (n) per block
#define NTHR 512         // 8 waves
#define XU_P 264         // u tile pitch (u16)
#define SC_P 264         // state-chunk pitch (u16)

__device__ __align__(16) float g_lam[2 * SD];            // lam_re | lam_im
__device__ __align__(16) u16   g_W1[1024 * IN_DIM];      // bf16
__device__ __align__(16) u16   g_Wy[OUT_DIM * 1280];     // bf16

__device__ __forceinline__ u16 f2b(float f) {
    union { float f; unsigned int u; } v; v.f = f;
    unsigned int r = v.u + 0x7FFFu + ((v.u >> 16) & 1u);   // RNE
    return (u16)(r >> 16);
}
__device__ __forceinline__ ushort4 f2b4(f32x4 v) {
    ushort4 b;
    b.x = f2b(v[0]); b.y = f2b(v[1]); b.z = f2b(v[2]); b.w = f2b(v[3]);
    return b;
}

// --- combined prep (single launch) -----------------------------------------
// blocks [0,1024): W1 row b.  blocks [1024,1280): Wy row b-1024.
// blocks [1280,1282): lam.
__global__ void prep_all(const float* __restrict__ nu_log,
                         const float* __restrict__ theta_log,
                         const float* __restrict__ gamma_log,
                         const float* __restrict__ B_re, const float* __restrict__ B_im,
                         const float* __restrict__ C_re, const float* __restrict__ C_im,
                         const float* __restrict__ D) {
    int b = blockIdx.x, t = threadIdx.x;
    if (b < 1024) {
        int w = b & 255;
        int h = (b >> 8) * 128 + (w & 127);
        float g = expf(gamma_log[h]);
        const float* src = (w < 128) ? B_re : B_im;
        g_W1[b * IN_DIM + t] = f2b(src[h * IN_DIM + t] * g);
    } else if (b < 1280) {
        int o = b - 1024;
        #pragma unroll
        for (int it = 0; it < 5; ++it) {
            int c = it * 256 + t;
            float v;
            if (c < 1024) {
                int s = c >> 8, k = c & 255;
                v = (k < 128) ? C_re[o * SD + s * 128 + k]
                              : -C_im[o * SD + s * 128 + (k - 128)];
            } else {
                v = D[o * IN_DIM + (c - 1024)];
            }
            g_Wy[(size_t)o * 1280 + c] = f2b(v);
        }
    } else {
        int h = (b - 1280) * 256 + t;          // [0,512)
        float mod = expf(-expf(nu_log[h]));
        float th  = expf(theta_log[h]);
        g_lam[h]      = mod * cosf(th);
        g_lam[SD + h] = mod * sinf(th);
    }
}

// --- main fused kernel ------------------------------------------------------
__global__ __launch_bounds__(NTHR, 6) void lru_main(
    const float* __restrict__ u, const float* __restrict__ x0_re,
    const float* __restrict__ x0_im,
    float* __restrict__ y_out, float* __restrict__ st_out,
    long long st_limit)     // floats available in the state region of d_out
{
    __shared__ __align__(16) u16 Xu[ROWS * XU_P];   // u tile bf16
    __shared__ __align__(16) u16 Sc[ROWS * SC_P];   // state chunk bf16 (re|im)

    const int tid  = threadIdx.x;
    const int wv   = tid >> 6;          // [0,8)
    const int lane = tid & 63;
    const int quad = lane >> 4;
    const int l16  = lane & 15;
    const int kq   = quad * 8;
    const size_t n0 = (size_t)blockIdx.x * ROWS;

    const int  Mb    = wv * 32;         // wave's M base within a 256-col chunk
    const bool is_im = (wv >= 4);       // waves 0-3: re plane, 4-7: im plane

    // stage u tile -> bf16 LDS (32x256, f32x4 loads)
    #pragma unroll
    for (int i = 0; i < 4; ++i) {
        int it = tid + i * NTHR;              // 2048 items
        int r = it >> 6, c4 = it & 63;
        f32x4 v = ((const f32x4*)(u + (n0 + r) * IN_DIM))[c4];
        *(ushort4*)(&Xu[r * XU_P + c4 * 4]) = f2b4(v);
    }
    __syncthreads();

    f32x4 accy[2][2];
    #pragma unroll
    for (int ot = 0; ot < 2; ++ot)
        #pragma unroll
        for (int nt = 0; nt < 2; ++nt)
            accy[ot][nt] = f32x4{0.f, 0.f, 0.f, 0.f};

    for (int s = 0; s < 4; ++s) {
        // ---- GEMM-A: Bu[M=256(re|im)][n=32] = W1_chunk @ u_tile^T
        f32x4 acc[2][2];
        #pragma unroll
        for (int ht = 0; ht < 2; ++ht)
            #pragma unroll
            for (int nt = 0; nt < 2; ++nt)
                acc[ht][nt] = f32x4{0.f, 0.f, 0.f, 0.f};
        const u16* w1b = g_W1 + (size_t)(s * 256 + Mb) * IN_DIM;
        #pragma unroll
        for (int k0 = 0; k0 < IN_DIM; k0 += 32) {
            bf16x8 a[2], b[2];
            #pragma unroll
            for (int ht = 0; ht < 2; ++ht)
                a[ht] = *(const bf16x8*)(w1b + (ht * 16 + l16) * IN_DIM + k0 + kq);
            #pragma unroll
            for (int nt = 0; nt < 2; ++nt)
                b[nt] = *(const bf16x8*)(&Xu[(nt * 16 + l16) * XU_P + k0 + kq]);
            #pragma unroll
            for (int ht = 0; ht < 2; ++ht)
                #pragma unroll
                for (int nt = 0; nt < 2; ++nt)
                    acc[ht][nt] = __builtin_amdgcn_mfma_f32_16x16x32_bf16(
                        a[ht], b[nt], acc[ht][nt], 0, 0, 0);
        }
        __syncthreads();   // barrier A: previous chunk's Sc readers are done

        // ---- epilogue: state = lam*x0 + Bu, direct f32x4 stores, bf16 -> Sc
        #pragma unroll
        for (int ht = 0; ht < 2; ++ht) {
            #pragma unroll
            for (int nt = 0; nt < 2; ++nt) {
                const int hM = Mb + ht * 16 + quad * 4;    // [0,256) chunk col
                const int h  = s * 128 + (hM & 127);       // state index
                const int n  = nt * 16 + l16;
                const size_t roff = (n0 + n) * SD + h;
                f32x4 xr  = *(const f32x4*)(x0_re + roff);
                f32x4 xi  = *(const f32x4*)(x0_im + roff);
                f32x4 lre = *(const f32x4*)(g_lam + h);
                f32x4 lim = *(const f32x4*)(g_lam + SD + h);
                f32x4 sv;
                if (is_im) sv = lre * xi + lim * xr + acc[ht][nt];
                else       sv = lre * xr - lim * xi + acc[ht][nt];
                const long long idx = (is_im ? (long long)N_ROWS * SD : 0ll)
                                    + (long long)roff;
                if (idx + 3 < st_limit) {
                    *(f32x4*)(st_out + idx) = sv;
                } else {
                    #pragma unroll
                    for (int k = 0; k < 4; ++k)
                        if (idx + k < st_limit) st_out[idx + k] = sv[k];
                }
                *(ushort4*)(&Sc[n * SC_P + hM]) = f2b4(sv);
            }
        }
        __syncthreads();   // barrier B: Sc chunk ready

        // ---- partial y-GEMM: accy += Wy_chunk @ Sc^T
        #pragma unroll
        for (int k0 = 0; k0 < 256; k0 += 32) {
            bf16x8 a[2], b[2];
            #pragma unroll
            for (int ot = 0; ot < 2; ++ot)
                a[ot] = *(const bf16x8*)(g_Wy + (size_t)(Mb + ot * 16 + l16) * 1280
                                         + s * 256 + k0 + kq);
            #pragma unroll
            for (int nt = 0; nt < 2; ++nt)
                b[nt] = *(const bf16x8*)(&Sc[(nt * 16 + l16) * SC_P + k0 + kq]);
            #pragma unroll
            for (int ot = 0; ot < 2; ++ot)
                #pragma unroll
                for (int nt = 0; nt < 2; ++nt)
                    accy[ot][nt] = __builtin_amdgcn_mfma_f32_16x16x32_bf16(
                        a[ot], b[nt], accy[ot][nt], 0, 0, 0);
        }
    }

    // ---- y u-part: accy += D @ u_tile^T
    #pragma unroll
    for (int k0 = 0; k0 < IN_DIM; k0 += 32) {
        bf16x8 a[2], b[2];
        #pragma unroll
        for (int ot = 0; ot < 2; ++ot)
            a[ot] = *(const bf16x8*)(g_Wy + (size_t)(Mb + ot * 16 + l16) * 1280
                                     + 1024 + k0 + kq);
        #pragma unroll
        for (int nt = 0; nt < 2; ++nt)
            b[nt] = *(const bf16x8*)(&Xu[(nt * 16 + l16) * XU_P + k0 + kq]);
        #pragma unroll
        for (int ot = 0; ot < 2; ++ot)
            #pragma unroll
            for (int nt = 0; nt < 2; ++nt)
                accy[ot][nt] = __builtin_amdgcn_mfma_f32_16x16x32_bf16(
                    a[ot], b[nt], accy[ot][nt], 0, 0, 0);
    }

    // ---- y store: lane owns y[o4..o4+3][n] -> direct f32x4, 64B-coalesced
    #pragma unroll
    for (int ot = 0; ot < 2; ++ot) {
        #pragma unroll
        for (int nt = 0; nt < 2; ++nt) {
            const int o4 = Mb + ot * 16 + quad * 4;
            const int n  = nt * 16 + l16;
            *(f32x4*)(y_out + (n0 + n) * OUT_DIM + o4) = accy[ot][nt];
        }
    }
}

extern "C" void kernel_launch(void* const* d_in, const int* in_sizes, int n_in,
                              void* d_out, int out_size, void* d_ws, size_t ws_size,
                              hipStream_t stream) {
    const float* u         = (const float*)d_in[0];
    const float* x0_re     = (const float*)d_in[1];
    const float* x0_im     = (const float*)d_in[2];
    const float* nu_log    = (const float*)d_in[3];
    const float* theta_log = (const float*)d_in[4];
    const float* gamma_log = (const float*)d_in[5];
    const float* B_re      = (const float*)d_in[6];
    const float* B_im      = (const float*)d_in[7];
    const float* C_re      = (const float*)d_in[8];
    const float* C_im      = (const float*)d_in[9];
    const float* D         = (const float*)d_in[10];

    float* y_out  = (float*)d_out;
    float* st_out = y_out + (size_t)N_ROWS * OUT_DIM;
    long long st_limit = (long long)out_size - (long long)N_ROWS * OUT_DIM;

    prep_all<<<1282, 256, 0, stream>>>(nu_log, theta_log, gamma_log,
                                       B_re, B_im, C_re, C_im, D);
    lru_main<<<N_ROWS / ROWS, NTHR, 0, stream>>>(u, x0_re, x0_im,
                                                 y_out, st_out, st_limit);
}